// Round 3
// baseline (2930.713 us; speedup 1.0000x reference)
//
#include <hip/hip_runtime.h>

#define N_NODES 50000
#define N_EDGES 600000
#define DIM     128
#define RR      4
#define LL      2
#define GG      512
#define CC      8

// ---------- bf16 <-> f32 helpers (no hip_bf16.h dependency) ----------
__device__ __forceinline__ float bf16_to_f(unsigned short u) {
    unsigned int v = ((unsigned int)u) << 16;
    return __uint_as_float(v);
}
__device__ __forceinline__ unsigned short f_to_bf16(float f) {
    unsigned int u = __float_as_uint(f);
    u += 0x7FFFu + ((u >> 16) & 1u);   // round-to-nearest-even
    return (unsigned short)(u >> 16);
}
// adaptive load/store: isbf=1 -> buffer is packed bf16, else fp32
__device__ __forceinline__ float loadf(const void* p, long i, int isbf) {
    if (isbf) return bf16_to_f(((const unsigned short*)p)[i]);
    return ((const float*)p)[i];
}
__device__ __forceinline__ void storef(void* p, long i, float v, int isbf) {
    if (isbf) ((unsigned short*)p)[i] = f_to_bf16(v);
    else      ((float*)p)[i] = v;
}

// ---------- dtype detection ----------
// If x is packed bf16, the LOW u16 of each 32-bit word is a real bf16 value of
// N(0,1) data -> exponent field in [110,133] ~always. If x is fp32, the low
// u16 is mantissa noise -> sane exponent ~9% of the time.
__global__ void cg_detect(const unsigned int* __restrict__ xw, int* __restrict__ flag) {
    __shared__ int cnt;
    if (threadIdx.x == 0) cnt = 0;
    __syncthreads();
    unsigned int w = xw[threadIdx.x];
    unsigned int e = (w >> 7) & 0xFFu;          // exponent of low-u16-as-bf16
    int sane = (e >= 110u && e <= 133u) ? 1 : 0;
    atomicAdd(&cnt, sane);
    __syncthreads();
    if (threadIdx.x == 0) *flag = (cnt >= 128) ? 1 : 0;
}

// ---------- zero a float region ----------
__global__ void cg_zero(float* __restrict__ p, int n) {
    int t = blockIdx.x * 256 + threadIdx.x;
    if (t < n) p[t] = 0.0f;
}

// ---------- M2[l,r,d,o] = sum_k conv_W[l,r,d,k] * fuse_W[r*128+k, o] ----------
__global__ void cg_make_M2(const void* __restrict__ conv_W, const void* __restrict__ fuse_W,
                           const int* __restrict__ flagp, float* __restrict__ M2) {
    int b  = blockIdx.x;            // lr*128 + d
    int d  = b & 127;
    int lr = b >> 7;                // l*RR + r
    int r  = lr & 3;
    int o  = threadIdx.x;
    int isbf = *flagp;
    float acc = 0.0f;
    for (int k = 0; k < DIM; k++) {
        float cw = loadf(conv_W, (long)(lr * DIM + d) * DIM + k, isbf);
        float fw = loadf(fuse_W, (long)(r * DIM + k) * DIM + o, isbf);
        acc += cw * fw;
    }
    M2[(long)b * DIM + o] = acc;    // [L*R][128][128]
}

// ---------- cvec[l,o] = sum_rk conv_b[l,rk]*fuse_W[rk,o] + fuse_b[o] ----------
__global__ void cg_make_c(const void* __restrict__ conv_b, const void* __restrict__ fuse_W,
                          const void* __restrict__ fuse_b, const int* __restrict__ flagp,
                          float* __restrict__ cvec) {
    int l = blockIdx.x;
    int o = threadIdx.x;
    int isbf = *flagp;
    float acc = loadf(fuse_b, o, isbf);
    for (int rk = 0; rk < RR * DIM; rk++) {
        acc += loadf(conv_b, (long)l * RR * DIM + rk, isbf)
             * loadf(fuse_W, (long)rk * DIM + o, isbf);
    }
    cvec[l * DIM + o] = acc;
}

// ---------- h[n,o] = sum_d x[n,d]*W_het[t,d,o] + b_het[t,o] ----------
__global__ void cg_hetero(const void* __restrict__ x, const void* __restrict__ W_het,
                          const void* __restrict__ b_het, const int* __restrict__ node_type,
                          const int* __restrict__ flagp, float* __restrict__ h) {
    __shared__ float xs[DIM];
    int n = blockIdx.x;
    int o = threadIdx.x;
    int isbf = *flagp;
    int t = node_type[n];
    xs[o] = loadf(x, (long)n * DIM + o, isbf);
    __syncthreads();
    float acc = loadf(b_het, t * DIM + o, isbf);
    for (int d = 0; d < DIM; d++) {
        acc += xs[d] * loadf(W_het, ((long)t * DIM + d) * DIM + o, isbf);
    }
    h[(long)n * DIM + o] = acc;
}

// ---------- Pr[n,o] = sum_d h[n,d] * M2lr[d,o]  (16 nodes per block) ----------
__global__ void cg_pgemm(const float* __restrict__ h, const float* __restrict__ M2lr,
                         float* __restrict__ Pr) {
    __shared__ float hs[16][DIM];
    int o  = threadIdx.x;
    int n0 = blockIdx.x * 16;
    for (int j = 0; j < 16; j++) {
        int n = n0 + j;
        hs[j][o] = (n < N_NODES) ? h[(long)n * DIM + o] : 0.0f;
    }
    __syncthreads();
    float acc[16];
    for (int j = 0; j < 16; j++) acc[j] = 0.0f;
    for (int d = 0; d < DIM; d++) {
        float m = M2lr[d * DIM + o];
        for (int j = 0; j < 16; j++) acc[j] += hs[j][d] * m;
    }
    for (int j = 0; j < 16; j++) {
        int n = n0 + j;
        if (n < N_NODES) Pr[(long)n * DIM + o] = acc[j];
    }
}

// ---------- Y[dst,:] += Pr[src,:] for edges of relation r ----------
__global__ void cg_scatter(const float* __restrict__ Pr, const int* __restrict__ edge_index,
                           const int* __restrict__ edge_type, int r, float* __restrict__ Y) {
    long t = (long)blockIdx.x * 256 + threadIdx.x;
    if (t >= (long)N_EDGES * 32) return;
    int e    = (int)(t >> 5);
    int part = (int)(t & 31);
    if (edge_type[e] != r) return;
    int s = edge_index[e];
    int d = edge_index[N_EDGES + e];
    const float* srcp = Pr + (long)s * DIM + part * 4;
    float*       dstp = Y  + (long)d * DIM + part * 4;
    atomicAdd(dstp + 0, srcp[0]);
    atomicAdd(dstp + 1, srcp[1]);
    atomicAdd(dstp + 2, srcp[2]);
    atomicAdd(dstp + 3, srcp[3]);
}

// ---------- h = relu(Y + cvec[l]) ----------
__global__ void cg_relu(const float* __restrict__ Y, const float* __restrict__ cv,
                        float* __restrict__ h) {
    int t = blockIdx.x * 256 + threadIdx.x;
    if (t >= N_NODES * DIM) return;
    float v = Y[t] + cv[t & (DIM - 1)];
    h[t] = v > 0.0f ? v : 0.0f;
}

// ---------- embacc[batch[n],:] += h[n,:]; counts[batch[n]] += 1 ----------
__global__ void cg_pool(const float* __restrict__ h, const int* __restrict__ batch,
                        float* __restrict__ embacc, float* __restrict__ counts) {
    long t = (long)blockIdx.x * 256 + threadIdx.x;
    if (t >= (long)N_NODES * 32) return;
    int n    = (int)(t >> 5);
    int part = (int)(t & 31);
    int g = batch[n];
    const float* srcp = h + (long)n * DIM + part * 4;
    float*       dstp = embacc + (long)g * DIM + part * 4;
    atomicAdd(dstp + 0, srcp[0]);
    atomicAdd(dstp + 1, srcp[1]);
    atomicAdd(dstp + 2, srcp[2]);
    atomicAdd(dstp + 3, srcp[3]);
    if (part == 0) atomicAdd(&counts[g], 1.0f);
}

// ---------- emb = embacc / max(counts,1); write out[0:G*D] ----------
__global__ void cg_finalize(float* __restrict__ embacc, const float* __restrict__ counts,
                            const int* __restrict__ flagp, void* __restrict__ out) {
    int t = blockIdx.x * 256 + threadIdx.x;
    if (t >= GG * DIM) return;
    int g = t >> 7;
    float c = counts[g];
    float e = embacc[t] / (c > 1.0f ? c : 1.0f);
    embacc[t] = e;
    storef(out, t, e, *flagp);
}

// ---------- logits = emb @ cls_W + cls_b; write out[G*D : G*D+G*C] ----------
__global__ void cg_logits(const float* __restrict__ emb, const void* __restrict__ cls_W,
                          const void* __restrict__ cls_b, const int* __restrict__ flagp,
                          void* __restrict__ out) {
    int t = blockIdx.x * 256 + threadIdx.x;
    if (t >= GG * CC) return;
    int g  = t >> 3;
    int cc = t & 7;
    int isbf = *flagp;
    float acc = loadf(cls_b, cc, isbf);
    for (int k = 0; k < DIM; k++) {
        acc += emb[(long)g * DIM + k] * loadf(cls_W, (long)k * CC + cc, isbf);
    }
    storef(out, (long)GG * DIM + t, acc, isbf);
}

extern "C" void kernel_launch(void* const* d_in, const int* in_sizes, int n_in,
                              void* d_out, int out_size, void* d_ws, size_t ws_size,
                              hipStream_t stream) {
    const void* x      = d_in[0];
    const void* W_het  = d_in[1];
    const void* b_het  = d_in[2];
    const void* conv_W = d_in[3];
    const void* conv_b = d_in[4];
    const void* fuse_W = d_in[5];
    const void* fuse_b = d_in[6];
    const void* cls_W  = d_in[7];
    const void* cls_b  = d_in[8];
    const int* node_type  = (const int*)d_in[9];
    const int* edge_index = (const int*)d_in[10];
    const int* edge_type  = (const int*)d_in[11];
    const int* batch      = (const int*)d_in[12];

    // workspace layout (bytes)
    char* base = (char*)d_ws;
    float* h      = (float*)(base + 0);            // N*128 f32 = 25,600,000 B
    float* Y      = (float*)(base + 25600000);     // N*128 f32 = 25,600,000 B
    float* Pr     = (float*)(base + 51200000);     // N*128 f32 = 25,600,000 B
    float* M2     = (float*)(base + 76800000);     // 8*128*128 f32 = 524,288 B
    float* cvec   = (float*)(base + 77324288);     // 2*128 f32 = 1,024 B
    float* embacc = (float*)(base + 77325312);     // G*128 f32 = 262,144 B
    float* counts = (float*)(base + 77587456);     // G f32 = 2,048 B
    int*   flag   = (int*)  (base + 77589504);     // 4 B   (total ~77.6 MB)

    cg_detect<<<1, 256, 0, stream>>>((const unsigned int*)x, flag);
    cg_make_M2<<<LL * RR * DIM, DIM, 0, stream>>>(conv_W, fuse_W, flag, M2);
    cg_make_c<<<LL, DIM, 0, stream>>>(conv_b, fuse_W, fuse_b, flag, cvec);
    cg_hetero<<<N_NODES, DIM, 0, stream>>>(x, W_het, b_het, node_type, flag, h);

    for (int l = 0; l < LL; l++) {
        cg_zero<<<(N_NODES * DIM + 255) / 256, 256, 0, stream>>>(Y, N_NODES * DIM);
        for (int r = 0; r < RR; r++) {
            cg_pgemm<<<(N_NODES + 15) / 16, DIM, 0, stream>>>(
                h, M2 + (long)(l * RR + r) * DIM * DIM, Pr);
            cg_scatter<<<(int)(((long)N_EDGES * 32 + 255) / 256), 256, 0, stream>>>(
                Pr, edge_index, edge_type, r, Y);
        }
        cg_relu<<<(N_NODES * DIM + 255) / 256, 256, 0, stream>>>(Y, cvec + l * DIM, h);
    }

    cg_zero<<<(GG * DIM + GG + 255) / 256, 256, 0, stream>>>(embacc, GG * DIM + GG);
    cg_pool<<<(int)(((long)N_NODES * 32 + 255) / 256), 256, 0, stream>>>(h, batch, embacc, counts);
    cg_finalize<<<(GG * DIM + 255) / 256, 256, 0, stream>>>(embacc, counts, flag, d_out);
    cg_logits<<<(GG * CC + 255) / 256, 256, 0, stream>>>(embacc, cls_W, cls_b, flag, d_out);
}

// Round 4
// 850.623 us; speedup vs baseline: 3.4454x; 3.4454x over previous
//
#include <hip/hip_runtime.h>

#define N_NODES 50000
#define N_EDGES 600000
#define DIM     128
#define RR      4
#define LL      2
#define GG      512
#define CC      8

// ---------- bf16 <-> f32 helpers (no hip_bf16.h dependency) ----------
__device__ __forceinline__ float bf16_to_f(unsigned short u) {
    return __uint_as_float(((unsigned int)u) << 16);
}
__device__ __forceinline__ unsigned short f_to_bf16(float f) {
    unsigned int u = __float_as_uint(f);
    u += 0x7FFFu + ((u >> 16) & 1u);   // round-to-nearest-even
    return (unsigned short)(u >> 16);
}
// adaptive load/store: isbf=1 -> buffer is packed bf16, else fp32
__device__ __forceinline__ float loadf(const void* p, long i, int isbf) {
    if (isbf) return bf16_to_f(((const unsigned short*)p)[i]);
    return ((const float*)p)[i];
}
__device__ __forceinline__ void storef(void* p, long i, float v, int isbf) {
    if (isbf) ((unsigned short*)p)[i] = f_to_bf16(v);
    else      ((float*)p)[i] = v;
}

// ---------- dtype detection (same as round 3, it works) ----------
__global__ void cg_detect(const unsigned int* __restrict__ xw, int* __restrict__ flag) {
    __shared__ int cnt;
    if (threadIdx.x == 0) cnt = 0;
    __syncthreads();
    unsigned int w = xw[threadIdx.x];
    unsigned int e = (w >> 7) & 0xFFu;
    atomicAdd(&cnt, (e >= 110u && e <= 133u) ? 1 : 0);
    __syncthreads();
    if (threadIdx.x == 0) *flag = (cnt >= 128) ? 1 : 0;
}

__global__ void cg_zero_i(int* __restrict__ p, int n) {
    int t = blockIdx.x * 256 + threadIdx.x;
    if (t < n) p[t] = 0;
}

// ---------- CSR build: histogram by dst ----------
__global__ void cg_hist(const int* __restrict__ edge_index, int* __restrict__ deg) {
    int e = blockIdx.x * 256 + threadIdx.x;
    if (e >= N_EDGES) return;
    atomicAdd(&deg[edge_index[N_EDGES + e]], 1);
}

// ---------- CSR build: exclusive scan over 50000 degrees (1 block) ----------
#define SCAN_T 1024
__global__ void cg_scan(const int* __restrict__ deg, int* __restrict__ rowptr,
                        int* __restrict__ cursor) {
    __shared__ int part[SCAN_T];
    int tid = threadIdx.x;
    const int chunk = (N_NODES + SCAN_T - 1) / SCAN_T;   // 49
    int lo = tid * chunk;
    int hi = lo + chunk; if (hi > N_NODES) hi = N_NODES;
    int s = 0;
    for (int i = lo; i < hi; i++) s += deg[i];
    part[tid] = s;
    __syncthreads();
    for (int off = 1; off < SCAN_T; off <<= 1) {
        int add = (tid >= off) ? part[tid - off] : 0;
        __syncthreads();
        part[tid] += add;
        __syncthreads();
    }
    int run = (tid > 0) ? part[tid - 1] : 0;
    for (int i = lo; i < hi; i++) {
        rowptr[i] = run; cursor[i] = run;
        run += deg[i];
    }
    if (tid == SCAN_T - 1) rowptr[N_NODES] = part[SCAN_T - 1];
}

// ---------- CSR build: fill buckets; payload = src<<2 | r ----------
__global__ void cg_fill(const int* __restrict__ edge_index, const int* __restrict__ edge_type,
                        int* __restrict__ cursor, int* __restrict__ eidx) {
    int e = blockIdx.x * 256 + threadIdx.x;
    if (e >= N_EDGES) return;
    int d = edge_index[N_EDGES + e];
    int pos = atomicAdd(&cursor[d], 1);
    eidx[pos] = (edge_index[e] << 2) | edge_type[e];
}

// ---------- M2[lr][d][o] = sum_k conv_W[l,r,d,k] * fuse_W[r*128+k, o] ----------
__global__ void cg_make_M2(const void* __restrict__ conv_W, const void* __restrict__ fuse_W,
                           const int* __restrict__ flagp, float* __restrict__ M2) {
    int b  = blockIdx.x;            // lr*128 + d
    int d  = b & 127;
    int lr = b >> 7;
    int r  = lr & 3;
    int o  = threadIdx.x;
    int isbf = *flagp;
    float acc = 0.0f;
    for (int k = 0; k < DIM; k++) {
        acc += loadf(conv_W, (long)(lr * DIM + d) * DIM + k, isbf)
             * loadf(fuse_W, (long)(r * DIM + k) * DIM + o, isbf);
    }
    M2[(long)b * DIM + o] = acc;
}

// ---------- cvec[l,o] = sum_rk conv_b[l,rk]*fuse_W[rk,o] + fuse_b[o] ----------
__global__ void cg_make_c(const void* __restrict__ conv_b, const void* __restrict__ fuse_W,
                          const void* __restrict__ fuse_b, const int* __restrict__ flagp,
                          float* __restrict__ cvec) {
    int l = blockIdx.x;
    int o = threadIdx.x;
    int isbf = *flagp;
    float acc = loadf(fuse_b, o, isbf);
    for (int rk = 0; rk < RR * DIM; rk++) {
        acc += loadf(conv_b, (long)l * RR * DIM + rk, isbf)
             * loadf(fuse_W, (long)rk * DIM + o, isbf);
    }
    cvec[l * DIM + o] = acc;
}

// ---------- h[n,o] = sum_d x[n,d]*W_het[t,d,o] + b_het[t,o] ----------
__global__ void cg_hetero(const void* __restrict__ x, const void* __restrict__ W_het,
                          const void* __restrict__ b_het, const int* __restrict__ node_type,
                          const int* __restrict__ flagp, float* __restrict__ h) {
    __shared__ float xs[DIM];
    int n = blockIdx.x;
    int o = threadIdx.x;
    int isbf = *flagp;
    int t = node_type[n];
    xs[o] = loadf(x, (long)n * DIM + o, isbf);
    __syncthreads();
    float acc = loadf(b_het, t * DIM + o, isbf);
    for (int d = 0; d < DIM; d++) {
        acc += xs[d] * loadf(W_het, ((long)t * DIM + d) * DIM + o, isbf);
    }
    h[(long)n * DIM + o] = acc;
}

// ---------- P[n, r*128+o] = sum_d h[n,d]*M2[lr][d][o]  (bf16 out) ----------
__global__ void cg_pgemm(const float* __restrict__ h, const float* __restrict__ M2l,
                         unsigned short* __restrict__ P) {
    __shared__ float hs[16][DIM];
    int o  = threadIdx.x;
    int n0 = blockIdx.x * 16;
    int r  = blockIdx.y;
    const float* M = M2l + (long)r * DIM * DIM;
    for (int j = 0; j < 16; j++) {
        int n = n0 + j;
        hs[j][o] = (n < N_NODES) ? h[(long)n * DIM + o] : 0.0f;
    }
    __syncthreads();
    float acc[16];
#pragma unroll
    for (int j = 0; j < 16; j++) acc[j] = 0.0f;
    for (int d = 0; d < DIM; d++) {
        float m = M[d * DIM + o];
#pragma unroll
        for (int j = 0; j < 16; j++) acc[j] += hs[j][d] * m;
    }
    for (int j = 0; j < 16; j++) {
        int n = n0 + j;
        if (n < N_NODES) P[(long)n * (RR * DIM) + r * DIM + o] = f_to_bf16(acc[j]);
    }
}

// ---------- gather + bias + relu: h[n,:] = relu(sum_{e->n} P[src_e, r_e,:] + cv) ----------
__global__ void cg_gather(const unsigned short* __restrict__ P, const int* __restrict__ rowptr,
                          const int* __restrict__ eidx, const float* __restrict__ cv,
                          float* __restrict__ h) {
    int wid  = (blockIdx.x * 256 + threadIdx.x) >> 6;
    int lane = threadIdx.x & 63;
    if (wid >= N_NODES) return;
    int start = rowptr[wid];
    int end   = rowptr[wid + 1];
    float a0 = 0.0f, a1 = 0.0f;
    int j = start;
    for (; j + 1 < end; j += 2) {
        int v0 = eidx[j], v1 = eidx[j + 1];
        unsigned int w0 = *(const unsigned int*)(P + ((long)(v0 >> 2)) * (RR * DIM) + (v0 & 3) * DIM + 2 * lane);
        unsigned int w1 = *(const unsigned int*)(P + ((long)(v1 >> 2)) * (RR * DIM) + (v1 & 3) * DIM + 2 * lane);
        a0 += bf16_to_f((unsigned short)(w0 & 0xFFFFu)) + bf16_to_f((unsigned short)(w1 & 0xFFFFu));
        a1 += bf16_to_f((unsigned short)(w0 >> 16))     + bf16_to_f((unsigned short)(w1 >> 16));
    }
    if (j < end) {
        int v = eidx[j];
        unsigned int w = *(const unsigned int*)(P + ((long)(v >> 2)) * (RR * DIM) + (v & 3) * DIM + 2 * lane);
        a0 += bf16_to_f((unsigned short)(w & 0xFFFFu));
        a1 += bf16_to_f((unsigned short)(w >> 16));
    }
    int o = 2 * lane;
    float r0 = a0 + cv[o];
    float r1 = a1 + cv[o + 1];
    h[(long)wid * DIM + o]     = r0 > 0.0f ? r0 : 0.0f;
    h[(long)wid * DIM + o + 1] = r1 > 0.0f ? r1 : 0.0f;
}

// ---------- pooling via sorted-batch binary search: one block per graph ----------
__global__ void cg_pool2(const float* __restrict__ h, const int* __restrict__ batch,
                         float* __restrict__ embacc, const int* __restrict__ flagp,
                         void* __restrict__ out) {
    int g = blockIdx.x;
    int o = threadIdx.x;
    int lo = 0, hi = N_NODES;
    while (lo < hi) { int mid = (lo + hi) >> 1; if (batch[mid] < g) lo = mid + 1; else hi = mid; }
    int start = lo;
    hi = N_NODES;
    while (lo < hi) { int mid = (lo + hi) >> 1; if (batch[mid] < g + 1) lo = mid + 1; else hi = mid; }
    int end = lo;
    float acc = 0.0f;
    for (int n = start; n < end; n++) acc += h[(long)n * DIM + o];
    int cnt = end - start;
    float e = acc / (float)(cnt > 1 ? cnt : 1);
    embacc[(long)g * DIM + o] = e;
    storef(out, (long)g * DIM + o, e, *flagp);
}

// ---------- logits = emb @ cls_W + cls_b ----------
__global__ void cg_logits(const float* __restrict__ emb, const void* __restrict__ cls_W,
                          const void* __restrict__ cls_b, const int* __restrict__ flagp,
                          void* __restrict__ out) {
    int t = blockIdx.x * 256 + threadIdx.x;
    if (t >= GG * CC) return;
    int g  = t >> 3;
    int cc = t & 7;
    int isbf = *flagp;
    float acc = loadf(cls_b, cc, isbf);
    for (int k = 0; k < DIM; k++) {
        acc += emb[(long)g * DIM + k] * loadf(cls_W, (long)k * CC + cc, isbf);
    }
    storef(out, (long)GG * DIM + t, acc, isbf);
}

extern "C" void kernel_launch(void* const* d_in, const int* in_sizes, int n_in,
                              void* d_out, int out_size, void* d_ws, size_t ws_size,
                              hipStream_t stream) {
    const void* x      = d_in[0];
    const void* W_het  = d_in[1];
    const void* b_het  = d_in[2];
    const void* conv_W = d_in[3];
    const void* conv_b = d_in[4];
    const void* fuse_W = d_in[5];
    const void* fuse_b = d_in[6];
    const void* cls_W  = d_in[7];
    const void* cls_b  = d_in[8];
    const int* node_type  = (const int*)d_in[9];
    const int* edge_index = (const int*)d_in[10];
    const int* edge_type  = (const int*)d_in[11];
    const int* batch      = (const int*)d_in[12];

    // workspace layout (bytes, 16B aligned)
    char* base = (char*)d_ws;
    float*          h      = (float*)(base + 0);            // 25,600,000
    unsigned short* P      = (unsigned short*)(base + 25600000); // 51,200,000
    float*          M2     = (float*)(base + 76800000);     //    524,288
    float*          cvec   = (float*)(base + 77324288);     //      1,024
    float*          embacc = (float*)(base + 77325312);     //    262,144
    int*            rowptr = (int*)(base + 77587456);       //    200,016
    int*            cursor = (int*)(base + 77787472);       //    200,016
    int*            deg    = (int*)(base + 77987488);       //    200,016
    int*            eidx   = (int*)(base + 78187504);       //  2,400,000
    int*            flag   = (int*)(base + 80587504);       //          4

    cg_detect<<<1, 256, 0, stream>>>((const unsigned int*)x, flag);

    // CSR build (reused by both layers)
    cg_zero_i<<<(N_NODES + 255) / 256, 256, 0, stream>>>(deg, N_NODES);
    cg_hist<<<(N_EDGES + 255) / 256, 256, 0, stream>>>(edge_index, deg);
    cg_scan<<<1, SCAN_T, 0, stream>>>(deg, rowptr, cursor);
    cg_fill<<<(N_EDGES + 255) / 256, 256, 0, stream>>>(edge_index, edge_type, cursor, eidx);

    cg_make_M2<<<LL * RR * DIM, DIM, 0, stream>>>(conv_W, fuse_W, flag, M2);
    cg_make_c<<<LL, DIM, 0, stream>>>(conv_b, fuse_W, fuse_b, flag, cvec);
    cg_hetero<<<N_NODES, DIM, 0, stream>>>(x, W_het, b_het, node_type, flag, h);

    for (int l = 0; l < LL; l++) {
        cg_pgemm<<<dim3((N_NODES + 15) / 16, RR), DIM, 0, stream>>>(
            h, M2 + (long)l * RR * DIM * DIM, P);
        cg_gather<<<(N_NODES * 64 + 255) / 256, 256, 0, stream>>>(
            P, rowptr, eidx, cvec + l * DIM, h);
    }

    cg_pool2<<<GG, DIM, 0, stream>>>(h, batch, embacc, flag, d_out);
    cg_logits<<<(GG * CC + 255) / 256, 256, 0, stream>>>(embacc, cls_W, cls_b, flag, d_out);
}